// Round 8
// baseline (787.742 us; speedup 1.0000x reference)
//
#include <hip/hip_runtime.h>
#include <hip/hip_bf16.h>

// LSTM B=1024,T=512,F=64,H=128. R6 structure (331us): 256 blocks x 4 rows,
// 8 waves, 1 block/CU (R7 proved 2-block co-residency is register-infeasible;
// R5 proved launch_bounds(512,4) spills). R8 changes, both aimed at the
// serial per-step chain (R7 showed step time invariant to data volume ->
// chain-bound):
//  (a) ALL chunk x-work (global loads, bf16 pack, x-MFMAs, rotation) moved to
//      the chunk TAIL: after r==3's h ds_write, before the barrier -> runs in
//      the barrier-arrival shadow, off the post-barrier critical path.
//  (b) h-GEMM as 4 INDEPENDENT depth-1 MFMAs + 2-level add tree (was 2x
//      2-deep chains): one dependent-MFMA hop shorter.
// A-row rotation keeps D reg0 = own batch row (no selects). Raw lgkmcnt-only
// barriers. Bias folded into x-GEMM C seed. f32->bf16 2-op round-half-up.
// h_sm double-buffered, HPAD=144 (<=2-way LDS banks).

#define T_SEQ   512
#define F_IN    64
#define H_DIM   128
#define BB      4
#define NTHREADS 512
#define NG      4    // gate tiles per wave
#define KH      4    // h k-steps (K=128)
#define CH      4    // timestep chunk for batched x-GEMM
#define HPAD    144

typedef __bf16 bf16x8 __attribute__((ext_vector_type(8)));
typedef float  floatx4 __attribute__((ext_vector_type(4)));

__device__ __forceinline__ unsigned pk2_bf16(float a, float b) {
    unsigned ua = __builtin_bit_cast(unsigned, a);
    unsigned ub = __builtin_bit_cast(unsigned, b);
    return ((ua + 0x8000u) >> 16) | ((ub + 0x8000u) & 0xFFFF0000u);
}
__device__ __forceinline__ bf16x8 pack_frag(const float4 lo, const float4 hi) {
    union { unsigned u[4]; bf16x8 v; } r;
    r.u[0] = pk2_bf16(lo.x, lo.y);
    r.u[1] = pk2_bf16(lo.z, lo.w);
    r.u[2] = pk2_bf16(hi.x, hi.y);
    r.u[3] = pk2_bf16(hi.z, hi.w);
    return r.v;
}
__device__ __forceinline__ __bf16 bf16_rhu(float f) {
    unsigned u = __builtin_bit_cast(unsigned, f) + 0x8000u;
    unsigned short s = (unsigned short)(u >> 16);
    return __builtin_bit_cast(__bf16, s);
}
__device__ __forceinline__ __bf16 to_bf16(float f) {   // RNE, prologue only
    union { __hip_bfloat16 h; __bf16 b; } u;
    u.h = __float2bfloat16(f);
    return u.b;
}
__device__ __forceinline__ float fast_rcp(float x) { return __builtin_amdgcn_rcpf(x); }
__device__ __forceinline__ float sigmoid_f(float x) { return fast_rcp(1.0f + __expf(-x)); }
__device__ __forceinline__ float tanh_f(float x) {
    float e2 = __expf(2.0f * x);
    return (e2 - 1.0f) * fast_rcp(e2 + 1.0f);
}
// barrier with LDS visibility but NO vmcnt drain (x prefetch stays in flight)
__device__ __forceinline__ void lds_barrier() {
    asm volatile("s_waitcnt lgkmcnt(0)\n\ts_barrier" ::: "memory");
}

__global__ __launch_bounds__(NTHREADS, 2)
void lstm_fused_kernel(const float* __restrict__ x,
                       const float* __restrict__ W_ih,
                       const float* __restrict__ W_hh,
                       const float* __restrict__ b_ih,
                       const float* __restrict__ b_hh,
                       const float* __restrict__ W_out,
                       const float* __restrict__ b_out,
                       float* __restrict__ out)
{
    const int tid = threadIdx.x;
    const int w   = tid >> 6;
    const int l   = tid & 63;
    const int lm  = l & 15;        // A row within tile; B col-within-tile
    const int q   = l >> 4;        // quad: A k-sub; D row group; EW batch row
    const int b0  = blockIdx.x * BB;
    const int jcol = w * 16 + lm;  // hidden col this lane EWs (batch row q)
    const int rot  = (lm + (lm >> 2)) & 3;  // A-row rotation: D reg0 = own row

    __shared__ __align__(16) __bf16 h_sm[2][BB][HPAD];
    __shared__ float hf_sm[BB][H_DIM];

    // persistent weight B-frags: elem j = W[n][kb+j], n = g*128 + jcol,
    // kb = s*32 + q*8; s<4 -> W_hh, s>=4 -> W_ih(k-128). bias per gate.
    bf16x8 wf[NG][KH + 2];
    float  biasf[NG];
    #pragma unroll
    for (int g = 0; g < NG; ++g) {
        const int n = g * H_DIM + jcol;
        biasf[g] = b_ih[n] + b_hh[n];
        #pragma unroll
        for (int s = 0; s < KH + 2; ++s) {
            const int kb = s * 32 + q * 8;
            const float* src = (kb < 128) ? (W_hh + (size_t)n * 128 + kb)
                                          : (W_ih + (size_t)n * 64 + (kb - 128));
            const float4 f0 = *reinterpret_cast<const float4*>(src);
            const float4 f1 = *reinterpret_cast<const float4*>(src + 4);
            bf16x8 v;
            v[0] = to_bf16(f0.x); v[1] = to_bf16(f0.y);
            v[2] = to_bf16(f0.z); v[3] = to_bf16(f0.w);
            v[4] = to_bf16(f1.x); v[5] = to_bf16(f1.y);
            v[6] = to_bf16(f1.z); v[7] = to_bf16(f1.w);
            wf[g][s] = v;
        }
    }

    for (int idx = tid; idx < 2 * BB * HPAD; idx += NTHREADS)
        (&h_sm[0][0][0])[idx] = to_bf16(0.0f);

    // x-GEMM A source: A row m: br = m>>2, tsub = m&3 -> lane q reg r =
    // xg[row q][tc+r] (matches EW row q, no select)
    const float* xga = x + ((size_t)(b0 + (lm >> 2)) * T_SEQ + (lm & 3)) * F_IN + q * 8;

    // prologue: xg_cur = bias + xg(chunk 0); xld = x(chunk 1)
    floatx4 xg_cur[NG];
    {
        const float4 a0 = *reinterpret_cast<const float4*>(xga);
        const float4 a1 = *reinterpret_cast<const float4*>(xga + 4);
        const float4 a2 = *reinterpret_cast<const float4*>(xga + 32);
        const float4 a3 = *reinterpret_cast<const float4*>(xga + 36);
        const bf16x8 ax0 = pack_frag(a0, a1);
        const bf16x8 ax1 = pack_frag(a2, a3);
        #pragma unroll
        for (int g = 0; g < NG; ++g) {
            const floatx4 bias4 = {biasf[g], biasf[g], biasf[g], biasf[g]};
            xg_cur[g] = __builtin_amdgcn_mfma_f32_16x16x32_bf16(ax0, wf[g][KH + 0], bias4, 0, 0, 0);
            xg_cur[g] = __builtin_amdgcn_mfma_f32_16x16x32_bf16(ax1, wf[g][KH + 1], xg_cur[g], 0, 0, 0);
        }
    }
    float4 xld[4];
    {
        const float* xp = xga + CH * F_IN;
        xld[0] = *reinterpret_cast<const float4*>(xp);
        xld[1] = *reinterpret_cast<const float4*>(xp + 4);
        xld[2] = *reinterpret_cast<const float4*>(xp + 32);
        xld[3] = *reinterpret_cast<const float4*>(xp + 36);
    }

    float c = 0.0f, hval = 0.0f;
    const floatx4 zero4 = {0.f, 0.f, 0.f, 0.f};

    #pragma unroll 1
    for (int tc = 0; tc < T_SEQ; tc += CH) {
        #pragma unroll
        for (int r = 0; r < CH; ++r) {
            lds_barrier();   // h(tc+r-1) visible; x loads NOT drained

            // h-GEMM: 4 INDEPENDENT depth-1 MFMAs per gate; A rows rotated
            // so D reg0 = own batch row q.
            const int p = r & 1;
            const __bf16* hrow = &h_sm[p][rot][q * 8];
            bf16x8 ah[KH];
            #pragma unroll
            for (int s = 0; s < KH; ++s)
                ah[s] = *reinterpret_cast<const bf16x8*>(hrow + s * 32);
            floatx4 hacc[KH][NG];
            #pragma unroll
            for (int s = 0; s < KH; ++s) {
                #pragma unroll
                for (int g = 0; g < NG; ++g)
                    hacc[s][g] = __builtin_amdgcn_mfma_f32_16x16x32_bf16(
                        ah[s], wf[g][s], zero4, 0, 0, 0);
            }

            // gate = tree-sum of 4 own-row partials + (bias + xg)
            float gate[NG];
            #pragma unroll
            for (int g = 0; g < NG; ++g) {
                const float t0 = hacc[0][g][0] + hacc[1][g][0];
                const float t1 = hacc[2][g][0] + hacc[3][g][0];
                gate[g] = (t0 + t1) + xg_cur[g][r];
            }
            const float i_ = sigmoid_f(gate[0]);
            const float f_ = sigmoid_f(gate[1]);
            const float g_ = tanh_f(gate[2]);
            const float o_ = sigmoid_f(gate[3]);
            c    = f_ * c + i_ * g_;
            hval = o_ * tanh_f(c);
            h_sm[p ^ 1][q][jcol] = bf16_rhu(hval);
        }

        // ---- chunk tail: ALL x-work in the barrier-arrival shadow ----
        // (pure register/VMEM; no LDS dependency; executes while waves
        // drift toward the next barrier)
        {
            // xg(chunk C+1) from xld, bias-seeded
            const bf16x8 ax0 = pack_frag(xld[0], xld[1]);
            const bf16x8 ax1 = pack_frag(xld[2], xld[3]);
            #pragma unroll
            for (int g = 0; g < NG; ++g) {
                const floatx4 bias4 = {biasf[g], biasf[g], biasf[g], biasf[g]};
                xg_cur[g] = __builtin_amdgcn_mfma_f32_16x16x32_bf16(ax0, wf[g][KH + 0], bias4, 0, 0, 0);
                xg_cur[g] = __builtin_amdgcn_mfma_f32_16x16x32_bf16(ax1, wf[g][KH + 1], xg_cur[g], 0, 0, 0);
            }
            // loads for chunk C+2 (clamped); ~4 steps of flight, never
            // drained by a barrier (lgkmcnt-only barriers)
            const int tn = (tc + 2 * CH < T_SEQ) ? (tc + 2 * CH) : (T_SEQ - CH);
            const float* xp = xga + (size_t)tn * F_IN;
            xld[0] = *reinterpret_cast<const float4*>(xp);
            xld[1] = *reinterpret_cast<const float4*>(xp + 4);
            xld[2] = *reinterpret_cast<const float4*>(xp + 32);
            xld[3] = *reinterpret_cast<const float4*>(xp + 36);
        }
    }

    // projection: out[b] = h_T @ W_out^T + b_out
    hf_sm[q][jcol] = hval;
    __syncthreads();
    {
        const int m = tid >> 7, n = tid & 127;
        float sum = b_out[n];
        const float* wrow = W_out + (size_t)n * H_DIM;
        #pragma unroll 8
        for (int jj = 0; jj < H_DIM; ++jj)
            sum += hf_sm[m][jj] * wrow[jj];
        out[(size_t)(b0 + m) * H_DIM + n] = sum;
    }
}

extern "C" void kernel_launch(void* const* d_in, const int* in_sizes, int n_in,
                              void* d_out, int out_size, void* d_ws, size_t ws_size,
                              hipStream_t stream) {
    const float* x     = (const float*)d_in[0];
    const float* W_ih  = (const float*)d_in[1];
    const float* W_hh  = (const float*)d_in[2];
    const float* b_ih  = (const float*)d_in[3];
    const float* b_hh  = (const float*)d_in[4];
    const float* W_out = (const float*)d_in[5];
    const float* b_out = (const float*)d_in[6];
    float* out = (float*)d_out;

    lstm_fused_kernel<<<dim3(1024 / BB), dim3(NTHREADS), 0, stream>>>(
        x, W_ih, W_hh, b_ih, b_hh, W_out, b_out, out);
}